// Round 2
// baseline (1004.223 us; speedup 1.0000x reference)
//
#include <hip/hip_runtime.h>
#include <hip/hip_fp16.h>
#include <math.h>

// Problem constants (fixed by reference): B=16, L=8, A_CH=2, H=W=384, HID=64
#define HWDIM 384
#define PPX   (HWDIM * HWDIM)   // 147456 pixels per image
#define NBL   128               // B*L
#define NB    16

// ws layout: [0,272) float sums; conf f16 cache at byte offset 2048 (37.75 MB)
// sums: [0,128) mean_conf_sum  [128,256) overlap_sum  [256,272) demand_sum
#define WS_FLOATS   (2 * NBL + NB)
#define CONF_OFF_B  2048
#define CONF_BYTES  ((size_t)NBL * PPX * 2)

__device__ __forceinline__ float fast_sigmoid(float x) {
    return 1.0f / (1.0f + __expf(-x));
}

__global__ __launch_bounds__(256) void zero_kernel(float* __restrict__ s) {
    int i = blockIdx.x * blockDim.x + threadIdx.x;
    if (i < WS_FLOATS) s[i] = 0.0f;
}

// ---------------- Pass 1: conf = sigmoid(max(ch0,ch1)), cache f16, mean ----
// grid (144, 128), 256 thr, 4 px/thread (float4 vectorized)
__global__ __launch_bounds__(256) void conf_kernel(
    const float* __restrict__ psm, __half* __restrict__ confb,
    float* __restrict__ sums)
{
    const int bl = blockIdx.y;
    const int p0 = (blockIdx.x * 256 + threadIdx.x) * 4;
    const float* img0 = psm + (size_t)bl * (2 * PPX);

    float4 c0 = *(const float4*)(img0 + p0);
    float4 c1 = *(const float4*)(img0 + PPX + p0);

    float v0 = fast_sigmoid(fmaxf(c0.x, c1.x));
    float v1 = fast_sigmoid(fmaxf(c0.y, c1.y));
    float v2 = fast_sigmoid(fmaxf(c0.z, c1.z));
    float v3 = fast_sigmoid(fmaxf(c0.w, c1.w));

    union { __half h[4]; ushort4 u; } pk;
    pk.h[0] = __float2half(v0); pk.h[1] = __float2half(v1);
    pk.h[2] = __float2half(v2); pk.h[3] = __float2half(v3);
    *(ushort4*)(confb + (size_t)bl * PPX + p0) = pk.u;

    float s = (v0 + v1) + (v2 + v3);
    for (int o = 32; o > 0; o >>= 1) s += __shfl_down(s, o);
    if ((threadIdx.x & 63) == 0) atomicAdd(&sums[bl], s);
}

__device__ __forceinline__ float conf_sample_h(const __half* __restrict__ img,
                                               int yi, int xi) {
    bool valid = ((unsigned)xi < HWDIM) && ((unsigned)yi < HWDIM);
    int yc = min(max(yi, 0), HWDIM - 1);
    int xc = min(max(xi, 0), HWDIM - 1);
    float v = __half2float(img[yc * HWDIM + xc]);
    return valid ? v : 0.0f;
}

// ---------------- Pass 2: per b, read Di once, gather all 8 l warps --------
// grid (144, 16), 256 thr, 4 px/thread
__global__ __launch_bounds__(256) void overlap_kernel(
    const float* __restrict__ req, const float* __restrict__ naff,
    const __half* __restrict__ confb, float* __restrict__ sums)
{
    const int b = blockIdx.y;
    const int p0 = (blockIdx.x * 256 + threadIdx.x) * 4;
    const float* di_img = req + (size_t)(b * 8) * PPX;

    float4 di4 = *(const float4*)(di_img + p0);

    float A[8][6];
    #pragma unroll
    for (int l = 0; l < 8; ++l) {
        const int ab = (b * 64 + l) * 6;
        #pragma unroll
        for (int k = 0; k < 6; ++k) A[l][k] = naff[ab + k];
    }

    float acc[8];
    #pragma unroll
    for (int l = 0; l < 8; ++l) acc[l] = 0.0f;
    float sdi = (di4.x + di4.y) + (di4.z + di4.w);

    const float step = 2.0f / (float)(HWDIM - 1);
    const float half_ = 0.5f * (float)(HWDIM - 1);
    const int y = p0 / HWDIM;                 // 384 % 4 == 0: 4 px same row
    const int x = p0 - y * HWDIM;
    const float gyv = fmaf((float)y, step, -1.0f);

    #pragma unroll
    for (int j = 0; j < 4; ++j) {
        const float gxv = fmaf((float)(x + j), step, -1.0f);
        const float di = (&di4.x)[j];
        #pragma unroll
        for (int l = 0; l < 8; ++l) {
            float sx = A[l][0] * gxv + A[l][1] * gyv + A[l][2];
            float sy = A[l][3] * gxv + A[l][4] * gyv + A[l][5];
            float pxf = (sx + 1.0f) * half_;
            float pyf = (sy + 1.0f) * half_;
            float x0f = floorf(pxf), y0f = floorf(pyf);
            float wx = pxf - x0f, wy = pyf - y0f;
            int x0 = (int)x0f, y0 = (int)y0f;
            const __half* cimg = confb + (size_t)(b * 8 + l) * PPX;
            float v00 = conf_sample_h(cimg, y0,     x0);
            float v01 = conf_sample_h(cimg, y0,     x0 + 1);
            float v10 = conf_sample_h(cimg, y0 + 1, x0);
            float v11 = conf_sample_h(cimg, y0 + 1, x0 + 1);
            float top = v00 + wx * (v01 - v00);
            float bot = v10 + wx * (v11 - v10);
            acc[l] = fmaf(di, top + wy * (bot - top), acc[l]);
        }
    }

    #pragma unroll
    for (int l = 0; l < 8; ++l)
        for (int o = 32; o > 0; o >>= 1) acc[l] += __shfl_down(acc[l], o);
    for (int o = 32; o > 0; o >>= 1) sdi += __shfl_down(sdi, o);

    if ((threadIdx.x & 63) == 0) {
        #pragma unroll
        for (int l = 0; l < 8; ++l) atomicAdd(&sums[NBL + b * 8 + l], acc[l]);
        atomicAdd(&sums[2 * NBL + b], sdi);
    }
}

// ---------------- Fallback single-pass (round-1 kernel, used if ws small) --
__device__ __forceinline__ float conf_sample(const float* __restrict__ img0,
                                             int yi, int xi) {
    bool valid = ((unsigned)xi < HWDIM) && ((unsigned)yi < HWDIM);
    int yc = min(max(yi, 0), HWDIM - 1);
    int xc = min(max(xi, 0), HWDIM - 1);
    int off = yc * HWDIM + xc;
    return valid ? fast_sigmoid(fmaxf(img0[off], img0[off + PPX])) : 0.0f;
}

__global__ __launch_bounds__(256) void heavy_kernel(
    const float* __restrict__ psm, const float* __restrict__ req,
    const float* __restrict__ naff, float* __restrict__ sums)
{
    const int bl = blockIdx.y;
    const int b = bl >> 3;
    const int l = bl & 7;
    const float* img0   = psm + (size_t)bl * (2 * PPX);
    const float* di_img = req + (size_t)(b * 8) * PPX;
    const int abase = (b * 64 + l) * 6;
    const float a00 = naff[abase + 0], a01 = naff[abase + 1], a02 = naff[abase + 2];
    const float a10 = naff[abase + 3], a11 = naff[abase + 4], a12 = naff[abase + 5];
    float s_conf = 0.0f, s_ov = 0.0f, s_di = 0.0f;
    const int stride = blockDim.x * gridDim.x;
    const float step = 2.0f / (float)(HWDIM - 1);
    const float half_ = 0.5f * (float)(HWDIM - 1);
    for (int p = blockIdx.x * blockDim.x + threadIdx.x; p < PPX; p += stride) {
        int y = p / HWDIM;
        int x = p - y * HWDIM;
        float conf_own = fast_sigmoid(fmaxf(img0[p], img0[p + PPX]));
        s_conf += conf_own;
        float di = di_img[p];
        s_di += di;
        float gxv = fmaf((float)x, step, -1.0f);
        float gyv = fmaf((float)y, step, -1.0f);
        float sx = a00 * gxv + a01 * gyv + a02;
        float sy = a10 * gxv + a11 * gyv + a12;
        float pxf = (sx + 1.0f) * half_;
        float pyf = (sy + 1.0f) * half_;
        float x0f = floorf(pxf), y0f = floorf(pyf);
        float wx = pxf - x0f, wy = pyf - y0f;
        int x0 = (int)x0f, y0 = (int)y0f;
        float v00 = conf_sample(img0, y0,     x0);
        float v01 = conf_sample(img0, y0,     x0 + 1);
        float v10 = conf_sample(img0, y0 + 1, x0);
        float v11 = conf_sample(img0, y0 + 1, x0 + 1);
        float warped = v00 * (1.0f - wy) * (1.0f - wx) + v01 * (1.0f - wy) * wx
                     + v10 * wy * (1.0f - wx) + v11 * wy * wx;
        s_ov += di * warped;
    }
    for (int o = 32; o > 0; o >>= 1) {
        s_conf += __shfl_down(s_conf, o);
        s_ov   += __shfl_down(s_ov,   o);
        s_di   += __shfl_down(s_di,   o);
    }
    if ((threadIdx.x & 63) == 0) {
        atomicAdd(&sums[bl], s_conf);
        atomicAdd(&sums[NBL + bl], s_ov);
        if (l == 0) atomicAdd(&sums[2 * NBL + b], s_di);
    }
}

// ---------------- Tiny MLP head (one wave per (b,l)) -----------------------
__global__ __launch_bounds__(64) void mlp_kernel(
    const float* __restrict__ sums, const float* __restrict__ naff,
    const float* __restrict__ qW1, const float* __restrict__ qb1,
    const float* __restrict__ qW2, const float* __restrict__ qb2,
    const float* __restrict__ kW1, const float* __restrict__ kb1,
    const float* __restrict__ kW2, const float* __restrict__ kb2,
    const float* __restrict__ eW1, const float* __restrict__ eb1,
    const float* __restrict__ eW2, const float* __restrict__ eb2,
    float* __restrict__ out)
{
    const int bl = blockIdx.x;
    const int b = bl >> 3;
    const int l = bl & 7;
    const int t = threadIdx.x;
    const float invP = 1.0f / (float)PPX;

    const float demand = sums[2 * NBL + b] * invP;
    const float mc0    = sums[b * 8] * invP;
    const float mc     = sums[bl] * invP;
    const float ov     = sums[NBL + bl] * invP;

    const int abase = (b * 64 + l) * 6;
    const float dx = naff[abase + 2];
    const float dy = naff[abase + 5];
    const float dist = sqrtf(dx * dx + dy * dy);

    const int dbase  = (b * 64 + 9 * l) * 6;
    const int dbase0 = (b * 64) * 6;
    const float yawl = atan2f(naff[dbase + 3],  naff[dbase + 0]);
    const float yaw0 = atan2f(naff[dbase0 + 3], naff[dbase0 + 0]);
    const float tt = yaw0 - yawl;           // cos/sin(atan2(sin t,cos t))==cos/sin(t)
    const float cosd = cosf(tt), sind = sinf(tt);

    const float ego[8] = {mc0, demand, 0.0f, 0.0f, 1.0f, 0.0f, 0.0f, demand};
    const float fj[8]  = {mc, ov, dx, dy, cosd, sind, dist, demand};

    __shared__ float sh[64];
    __shared__ float qv[64];
    __shared__ float kv[64];

    float h = qb1[t];
    for (int i = 0; i < 8; ++i) h = fmaf(ego[i], qW1[i * 64 + t], h);
    h = fmaxf(h, 0.0f);
    sh[t] = h;
    __syncthreads();
    float q2 = qb2[t];
    for (int i = 0; i < 64; ++i) q2 = fmaf(sh[i], qW2[i * 64 + t], q2);
    qv[t] = q2;
    __syncthreads();

    float hk = kb1[t];
    for (int i = 0; i < 8; ++i) hk = fmaf(fj[i], kW1[i * 64 + t], hk);
    hk = fmaxf(hk, 0.0f);
    sh[t] = hk;
    __syncthreads();
    float k2 = kb2[t];
    for (int i = 0; i < 64; ++i) k2 = fmaf(sh[i], kW2[i * 64 + t], k2);
    kv[t] = k2;
    __syncthreads();

    float he = eb1[t];
    for (int i = 0; i < 64; ++i) he = fmaf(qv[i], eW1[i * 64 + t], he);
    for (int i = 0; i < 64; ++i) he = fmaf(kv[i], eW1[(64 + i) * 64 + t], he);
    he = fmaxf(he, 0.0f);

    float part = he * eW2[t];
    for (int o = 32; o > 0; o >>= 1) part += __shfl_down(part, o);

    if (t == 0) {
        float r;
        if (l == 0) {
            r = 0.0f;
        } else {
            float logit = part + eb2[0];
            r = 1.0f / (1.0f + expf(-logit));
            r = fminf(fmaxf(r, 0.0f), 1.0f);
        }
        out[bl] = r;
    }
}

extern "C" void kernel_launch(void* const* d_in, const int* in_sizes, int n_in,
                              void* d_out, int out_size, void* d_ws, size_t ws_size,
                              hipStream_t stream) {
    const float* psm  = (const float*)d_in[0];
    const float* req  = (const float*)d_in[1];
    const float* naff = (const float*)d_in[2];
    const float* qW1 = (const float*)d_in[4];
    const float* qb1 = (const float*)d_in[5];
    const float* qW2 = (const float*)d_in[6];
    const float* qb2 = (const float*)d_in[7];
    const float* kW1 = (const float*)d_in[8];
    const float* kb1 = (const float*)d_in[9];
    const float* kW2 = (const float*)d_in[10];
    const float* kb2 = (const float*)d_in[11];
    const float* eW1 = (const float*)d_in[12];
    const float* eb1 = (const float*)d_in[13];
    const float* eW2 = (const float*)d_in[14];
    const float* eb2 = (const float*)d_in[15];
    float* out  = (float*)d_out;
    float* sums = (float*)d_ws;

    hipLaunchKernelGGL(zero_kernel, dim3(2), dim3(256), 0, stream, sums);

    if (ws_size >= CONF_OFF_B + CONF_BYTES) {
        __half* confb = (__half*)((char*)d_ws + CONF_OFF_B);
        hipLaunchKernelGGL(conf_kernel, dim3(144, NBL), dim3(256), 0, stream,
                           psm, confb, sums);
        hipLaunchKernelGGL(overlap_kernel, dim3(144, NB), dim3(256), 0, stream,
                           req, naff, confb, sums);
    } else {
        hipLaunchKernelGGL(heavy_kernel, dim3(36, NBL), dim3(256), 0, stream,
                           psm, req, naff, sums);
    }

    hipLaunchKernelGGL(mlp_kernel, dim3(NBL), dim3(64), 0, stream,
                       sums, naff,
                       qW1, qb1, qW2, qb2, kW1, kb1, kW2, kb2,
                       eW1, eb1, eW2, eb2, out);
}

// Round 3
// 624.242 us; speedup vs baseline: 1.6087x; 1.6087x over previous
//
#include <hip/hip_runtime.h>
#include <hip/hip_fp16.h>
#include <math.h>

// Problem constants (fixed by reference): B=16, L=8, A_CH=2, H=W=384, HID=64
#define HWDIM 384
#define PPX   (HWDIM * HWDIM)   // 147456 px per image
#define NBL   128               // B*L
#define NB    16
#define NPART 144               // 36 blocks * 4 waves per image

// ws layout (floats):
//   [0,272)        sums: [0,128) mean_conf  [128,256) overlap  [256,272) demand
//   [1024, +18432) partA  (conf partials,  128 imgs * 144)
//   [19456,+18432) partO  (overlap partials)
//   [37888,+2304)  partD  (demand partials, 16 * 144)
// byte 262144:     conf f16 cache (128 * 147456 * 2 B = 37.75 MB)
#define SUMS_OFF    0
#define PART_A_OFF  1024
#define PART_O_OFF  19456
#define PART_D_OFF  37888
#define CONF_OFF_B  262144
#define CONF_BYTES  ((size_t)NBL * PPX * 2)

__device__ __forceinline__ float fast_sigmoid(float x) {
    return 1.0f / (1.0f + __expf(-x));
}

// ---- Pass 1: conf = sigmoid(max(ch0,ch1)) -> f16 cache + per-wave partial sum
// grid (36, 128), 256 thr, 16 px/thread. NO atomics: partial per wave.
__global__ __launch_bounds__(256) void conf_kernel(
    const float* __restrict__ psm, __half* __restrict__ confb,
    float* __restrict__ ws)
{
    const int bl = blockIdx.y;
    const int t  = threadIdx.x;
    const float* img0 = psm + (size_t)bl * (2 * PPX);
    const int p0 = blockIdx.x * 4096 + t * 4;

    // 8 independent float4 loads in flight
    float4 a[4], c[4];
    #pragma unroll
    for (int i = 0; i < 4; ++i) a[i] = *(const float4*)(img0 + p0 + i * 1024);
    #pragma unroll
    for (int i = 0; i < 4; ++i) c[i] = *(const float4*)(img0 + PPX + p0 + i * 1024);

    float s = 0.0f;
    #pragma unroll
    for (int i = 0; i < 4; ++i) {
        float v0 = fast_sigmoid(fmaxf(a[i].x, c[i].x));
        float v1 = fast_sigmoid(fmaxf(a[i].y, c[i].y));
        float v2 = fast_sigmoid(fmaxf(a[i].z, c[i].z));
        float v3 = fast_sigmoid(fmaxf(a[i].w, c[i].w));
        union { __half h[4]; ushort4 u; } pk;
        pk.h[0] = __float2half(v0); pk.h[1] = __float2half(v1);
        pk.h[2] = __float2half(v2); pk.h[3] = __float2half(v3);
        *(ushort4*)(confb + (size_t)bl * PPX + p0 + i * 1024) = pk.u;
        s += (v0 + v1) + (v2 + v3);
    }

    for (int o = 32; o > 0; o >>= 1) s += __shfl_down(s, o);
    if ((t & 63) == 0)
        ws[PART_A_OFF + bl * NPART + blockIdx.x * 4 + (t >> 6)] = s;
}

__device__ __forceinline__ float conf_sample_h(const __half* __restrict__ img,
                                               int yi, int xi) {
    bool valid = ((unsigned)xi < HWDIM) && ((unsigned)yi < HWDIM);
    int yc = min(max(yi, 0), HWDIM - 1);
    int xc = min(max(xi, 0), HWDIM - 1);
    float v = __half2float(img[yc * HWDIM + xc]);
    return valid ? v : 0.0f;
}

// ---- Pass 2: per b, read Di once, gather all 8 l warps. grid (36,16), 16 px/thr
__global__ __launch_bounds__(256) void overlap_kernel(
    const float* __restrict__ req, const float* __restrict__ naff,
    const __half* __restrict__ confb, float* __restrict__ ws)
{
    const int b = blockIdx.y;
    const int t = threadIdx.x;
    const float* di_img = req + (size_t)(b * 8) * PPX;
    const int p0 = blockIdx.x * 4096 + t * 4;

    float4 di[4];
    #pragma unroll
    for (int i = 0; i < 4; ++i) di[i] = *(const float4*)(di_img + p0 + i * 1024);

    float A[8][6];   // block-uniform -> compiler scalarizes
    #pragma unroll
    for (int l = 0; l < 8; ++l) {
        const int ab = (b * 64 + l) * 6;
        #pragma unroll
        for (int k = 0; k < 6; ++k) A[l][k] = naff[ab + k];
    }

    float acc[8];
    #pragma unroll
    for (int l = 0; l < 8; ++l) acc[l] = 0.0f;
    float sdi = 0.0f;

    const float step  = 2.0f / (float)(HWDIM - 1);
    const float half_ = 0.5f * (float)(HWDIM - 1);

    #pragma unroll
    for (int i = 0; i < 4; ++i) {
        const int p = p0 + i * 1024;
        const int y = p / HWDIM;
        const int x = p - y * HWDIM;       // 4 px share the row (384 % 4 == 0)
        const float gyv = fmaf((float)y, step, -1.0f);
        sdi += (di[i].x + di[i].y) + (di[i].z + di[i].w);

        #pragma unroll
        for (int j = 0; j < 4; ++j) {
            const float gxv = fmaf((float)(x + j), step, -1.0f);
            const float dv = (&di[i].x)[j];
            #pragma unroll
            for (int l = 0; l < 8; ++l) {
                float sx = A[l][0] * gxv + A[l][1] * gyv + A[l][2];
                float sy = A[l][3] * gxv + A[l][4] * gyv + A[l][5];
                float pxf = (sx + 1.0f) * half_;
                float pyf = (sy + 1.0f) * half_;
                float x0f = floorf(pxf), y0f = floorf(pyf);
                float wx = pxf - x0f, wy = pyf - y0f;
                int x0 = (int)x0f, y0 = (int)y0f;
                const __half* cimg = confb + (size_t)(b * 8 + l) * PPX;
                float v00 = conf_sample_h(cimg, y0,     x0);
                float v01 = conf_sample_h(cimg, y0,     x0 + 1);
                float v10 = conf_sample_h(cimg, y0 + 1, x0);
                float v11 = conf_sample_h(cimg, y0 + 1, x0 + 1);
                float top = v00 + wx * (v01 - v00);
                float bot = v10 + wx * (v11 - v10);
                acc[l] = fmaf(dv, top + wy * (bot - top), acc[l]);
            }
        }
    }

    #pragma unroll
    for (int l = 0; l < 8; ++l)
        for (int o = 32; o > 0; o >>= 1) acc[l] += __shfl_down(acc[l], o);
    for (int o = 32; o > 0; o >>= 1) sdi += __shfl_down(sdi, o);

    if ((t & 63) == 0) {
        const int pi = blockIdx.x * 4 + (t >> 6);
        #pragma unroll
        for (int l = 0; l < 8; ++l)
            ws[PART_O_OFF + (b * 8 + l) * NPART + pi] = acc[l];
        ws[PART_D_OFF + b * NPART + pi] = sdi;
    }
}

// ---- Fallback single-pass (ws too small for conf cache), atomic-free -------
__device__ __forceinline__ float conf_sample(const float* __restrict__ img0,
                                             int yi, int xi) {
    bool valid = ((unsigned)xi < HWDIM) && ((unsigned)yi < HWDIM);
    int yc = min(max(yi, 0), HWDIM - 1);
    int xc = min(max(xi, 0), HWDIM - 1);
    int off = yc * HWDIM + xc;
    return valid ? fast_sigmoid(fmaxf(img0[off], img0[off + PPX])) : 0.0f;
}

__global__ __launch_bounds__(256) void heavy_kernel(
    const float* __restrict__ psm, const float* __restrict__ req,
    const float* __restrict__ naff, float* __restrict__ ws)
{
    const int bl = blockIdx.y;
    const int b = bl >> 3;
    const int l = bl & 7;
    const float* img0   = psm + (size_t)bl * (2 * PPX);
    const float* di_img = req + (size_t)(b * 8) * PPX;
    const int abase = (b * 64 + l) * 6;
    const float a00 = naff[abase + 0], a01 = naff[abase + 1], a02 = naff[abase + 2];
    const float a10 = naff[abase + 3], a11 = naff[abase + 4], a12 = naff[abase + 5];
    float s_conf = 0.0f, s_ov = 0.0f, s_di = 0.0f;
    const int stride = 36 * 256;
    const float step = 2.0f / (float)(HWDIM - 1);
    const float half_ = 0.5f * (float)(HWDIM - 1);
    for (int p = blockIdx.x * 256 + threadIdx.x; p < PPX; p += stride) {
        int y = p / HWDIM;
        int x = p - y * HWDIM;
        s_conf += fast_sigmoid(fmaxf(img0[p], img0[p + PPX]));
        float di = di_img[p];
        s_di += di;
        float gxv = fmaf((float)x, step, -1.0f);
        float gyv = fmaf((float)y, step, -1.0f);
        float sx = a00 * gxv + a01 * gyv + a02;
        float sy = a10 * gxv + a11 * gyv + a12;
        float pxf = (sx + 1.0f) * half_;
        float pyf = (sy + 1.0f) * half_;
        float x0f = floorf(pxf), y0f = floorf(pyf);
        float wx = pxf - x0f, wy = pyf - y0f;
        int x0 = (int)x0f, y0 = (int)y0f;
        float v00 = conf_sample(img0, y0,     x0);
        float v01 = conf_sample(img0, y0,     x0 + 1);
        float v10 = conf_sample(img0, y0 + 1, x0);
        float v11 = conf_sample(img0, y0 + 1, x0 + 1);
        float top = v00 + wx * (v01 - v00);
        float bot = v10 + wx * (v11 - v10);
        s_ov = fmaf(di, top + wy * (bot - top), s_ov);
    }
    for (int o = 32; o > 0; o >>= 1) {
        s_conf += __shfl_down(s_conf, o);
        s_ov   += __shfl_down(s_ov,   o);
        s_di   += __shfl_down(s_di,   o);
    }
    if ((threadIdx.x & 63) == 0) {
        const int pi = blockIdx.x * 4 + (threadIdx.x >> 6);
        ws[PART_A_OFF + bl * NPART + pi] = s_conf;
        ws[PART_O_OFF + bl * NPART + pi] = s_ov;
        if (l == 0) ws[PART_D_OFF + b * NPART + pi] = s_di;
    }
}

// ---- Reduce partials -> sums[272] ------------------------------------------
__global__ __launch_bounds__(64) void reduce_kernel(float* __restrict__ ws) {
    const int idx = blockIdx.x * 64 + threadIdx.x;
    if (idx >= 2 * NBL + NB) return;
    const float* src;
    if (idx < NBL)            src = ws + PART_A_OFF + idx * NPART;
    else if (idx < 2 * NBL)   src = ws + PART_O_OFF + (idx - NBL) * NPART;
    else                      src = ws + PART_D_OFF + (idx - 2 * NBL) * NPART;
    float s = 0.0f;
    for (int k = 0; k < NPART; ++k) s += src[k];
    ws[SUMS_OFF + idx] = s;
}

// ---- Tiny MLP head (one wave per (b,l)) ------------------------------------
__global__ __launch_bounds__(64) void mlp_kernel(
    const float* __restrict__ sums, const float* __restrict__ naff,
    const float* __restrict__ qW1, const float* __restrict__ qb1,
    const float* __restrict__ qW2, const float* __restrict__ qb2,
    const float* __restrict__ kW1, const float* __restrict__ kb1,
    const float* __restrict__ kW2, const float* __restrict__ kb2,
    const float* __restrict__ eW1, const float* __restrict__ eb1,
    const float* __restrict__ eW2, const float* __restrict__ eb2,
    float* __restrict__ out)
{
    const int bl = blockIdx.x;
    const int b = bl >> 3;
    const int l = bl & 7;
    const int t = threadIdx.x;
    const float invP = 1.0f / (float)PPX;

    const float demand = sums[2 * NBL + b] * invP;
    const float mc0    = sums[b * 8] * invP;
    const float mc     = sums[bl] * invP;
    const float ov     = sums[NBL + bl] * invP;

    const int abase = (b * 64 + l) * 6;
    const float dx = naff[abase + 2];
    const float dy = naff[abase + 5];
    const float dist = sqrtf(dx * dx + dy * dy);

    const int dbase  = (b * 64 + 9 * l) * 6;
    const int dbase0 = (b * 64) * 6;
    const float yawl = atan2f(naff[dbase + 3],  naff[dbase + 0]);
    const float yaw0 = atan2f(naff[dbase0 + 3], naff[dbase0 + 0]);
    const float tt = yaw0 - yawl;        // cos/sin(atan2(sin t,cos t))==cos/sin(t)
    const float cosd = cosf(tt), sind = sinf(tt);

    const float ego[8] = {mc0, demand, 0.0f, 0.0f, 1.0f, 0.0f, 0.0f, demand};
    const float fj[8]  = {mc, ov, dx, dy, cosd, sind, dist, demand};

    __shared__ float sh[64];
    __shared__ float qv[64];
    __shared__ float kv[64];

    float h = qb1[t];
    for (int i = 0; i < 8; ++i) h = fmaf(ego[i], qW1[i * 64 + t], h);
    sh[t] = fmaxf(h, 0.0f);
    __syncthreads();
    float q2 = qb2[t];
    for (int i = 0; i < 64; ++i) q2 = fmaf(sh[i], qW2[i * 64 + t], q2);
    qv[t] = q2;
    __syncthreads();

    float hk = kb1[t];
    for (int i = 0; i < 8; ++i) hk = fmaf(fj[i], kW1[i * 64 + t], hk);
    sh[t] = fmaxf(hk, 0.0f);
    __syncthreads();
    float k2 = kb2[t];
    for (int i = 0; i < 64; ++i) k2 = fmaf(sh[i], kW2[i * 64 + t], k2);
    kv[t] = k2;
    __syncthreads();

    float he = eb1[t];
    for (int i = 0; i < 64; ++i) he = fmaf(qv[i], eW1[i * 64 + t], he);
    for (int i = 0; i < 64; ++i) he = fmaf(kv[i], eW1[(64 + i) * 64 + t], he);
    he = fmaxf(he, 0.0f);

    float part = he * eW2[t];
    for (int o = 32; o > 0; o >>= 1) part += __shfl_down(part, o);

    if (t == 0) {
        float r;
        if (l == 0) {
            r = 0.0f;                    // logits[:,0] = -1e9 -> sigmoid -> 0
        } else {
            float logit = part + eb2[0];
            r = 1.0f / (1.0f + expf(-logit));
            r = fminf(fmaxf(r, 0.0f), 1.0f);
        }
        out[bl] = r;
    }
}

extern "C" void kernel_launch(void* const* d_in, const int* in_sizes, int n_in,
                              void* d_out, int out_size, void* d_ws, size_t ws_size,
                              hipStream_t stream) {
    const float* psm  = (const float*)d_in[0];
    const float* req  = (const float*)d_in[1];
    const float* naff = (const float*)d_in[2];
    const float* qW1 = (const float*)d_in[4];
    const float* qb1 = (const float*)d_in[5];
    const float* qW2 = (const float*)d_in[6];
    const float* qb2 = (const float*)d_in[7];
    const float* kW1 = (const float*)d_in[8];
    const float* kb1 = (const float*)d_in[9];
    const float* kW2 = (const float*)d_in[10];
    const float* kb2 = (const float*)d_in[11];
    const float* eW1 = (const float*)d_in[12];
    const float* eb1 = (const float*)d_in[13];
    const float* eW2 = (const float*)d_in[14];
    const float* eb2 = (const float*)d_in[15];
    float* out = (float*)d_out;
    float* ws  = (float*)d_ws;

    if (ws_size >= CONF_OFF_B + CONF_BYTES) {
        __half* confb = (__half*)((char*)d_ws + CONF_OFF_B);
        hipLaunchKernelGGL(conf_kernel, dim3(36, NBL), dim3(256), 0, stream,
                           psm, confb, ws);
        hipLaunchKernelGGL(overlap_kernel, dim3(36, NB), dim3(256), 0, stream,
                           req, naff, confb, ws);
    } else {
        hipLaunchKernelGGL(heavy_kernel, dim3(36, NBL), dim3(256), 0, stream,
                           psm, req, naff, ws);
    }

    hipLaunchKernelGGL(reduce_kernel, dim3(5), dim3(64), 0, stream, ws);
    hipLaunchKernelGGL(mlp_kernel, dim3(NBL), dim3(64), 0, stream,
                       ws + SUMS_OFF, naff,
                       qW1, qb1, qW2, qb2, kW1, kb1, kW2, kb2,
                       eW1, eb1, eW2, eb2, out);
}

// Round 4
// 341.352 us; speedup vs baseline: 2.9419x; 1.8287x over previous
//
#include <hip/hip_runtime.h>
#include <hip/hip_fp16.h>
#include <math.h>

// Problem constants (fixed by reference): B=16, L=8, A_CH=2, H=W=384, HID=64
#define HWDIM 384
#define PPX   (HWDIM * HWDIM)   // 147456 px per image
#define NBL   128               // B*L
#define NB    16
#define NPART 576               // 144 blocks * 4 waves per image

// ws layout (floats):
//   [0,272)            sums: [0,128) mean_conf [128,256) overlap [256,272) demand
//   [1024,   +73728)   partA (conf partials,    128 * 576)
//   [74752,  +73728)   partO (overlap partials, 128 * 576)
//   [148480, +9216)    partD (demand partials,   16 * 576)
// byte 1048576: conf f16 cache (128 * 147456 * 2 B = 37.75 MB)
#define SUMS_OFF    0
#define PART_A_OFF  1024
#define PART_O_OFF  74752
#define PART_D_OFF  148480
#define CONF_OFF_B  1048576
#define CONF_BYTES  ((size_t)NBL * PPX * 2)

__device__ __forceinline__ float fast_sigmoid(float x) {
    return 1.0f / (1.0f + __expf(-x));
}

// force a block-uniform float into an SGPR
__device__ __forceinline__ float uload(const float* p) {
    union { float f; int i; } u;
    u.f = *p;
    u.i = __builtin_amdgcn_readfirstlane(u.i);
    return u.f;
}

// ---- Pass 1: conf = sigmoid(max(ch0,ch1)) -> f16 cache + per-wave partials
// grid (144, 128), 256 thr, 4 px/thread. No atomics.
__global__ __launch_bounds__(256) void conf_kernel(
    const float* __restrict__ psm, __half* __restrict__ confb,
    float* __restrict__ ws)
{
    const int bl = blockIdx.y;
    const int t  = threadIdx.x;
    const float* img0 = psm + (size_t)bl * (2 * PPX);
    const int p0 = blockIdx.x * 1024 + t * 4;

    float4 c0 = *(const float4*)(img0 + p0);
    float4 c1 = *(const float4*)(img0 + PPX + p0);

    float v0 = fast_sigmoid(fmaxf(c0.x, c1.x));
    float v1 = fast_sigmoid(fmaxf(c0.y, c1.y));
    float v2 = fast_sigmoid(fmaxf(c0.z, c1.z));
    float v3 = fast_sigmoid(fmaxf(c0.w, c1.w));

    union { __half h[4]; ushort4 u; } pk;
    pk.h[0] = __float2half(v0); pk.h[1] = __float2half(v1);
    pk.h[2] = __float2half(v2); pk.h[3] = __float2half(v3);
    *(ushort4*)(confb + (size_t)bl * PPX + p0) = pk.u;

    float s = (v0 + v1) + (v2 + v3);
    for (int o = 32; o > 0; o >>= 1) s += __shfl_down(s, o);
    if ((t & 63) == 0)
        ws[PART_A_OFF + bl * NPART + blockIdx.x * 4 + (t >> 6)] = s;
}

__device__ __forceinline__ float conf_sample_h(const __half* __restrict__ img,
                                               int yi, int xi) {
    bool valid = ((unsigned)xi < HWDIM) && ((unsigned)yi < HWDIM);
    int yc = min(max(yi, 0), HWDIM - 1);
    int xc = min(max(xi, 0), HWDIM - 1);
    float v = __half2float(img[yc * HWDIM + xc]);
    return valid ? v : 0.0f;
}

// ---- Pass 2: one (b,l) per blockIdx.y. grid (144, 128), 4 px/thread.
// Low VGPR: single accumulator, affine in SGPRs. Di re-read is L2/L3-local.
__global__ __launch_bounds__(256) void overlap_kernel(
    const float* __restrict__ req, const float* __restrict__ naff,
    const __half* __restrict__ confb, float* __restrict__ ws)
{
    const int bl = blockIdx.y;
    const int b = bl >> 3;
    const int l = bl & 7;
    const int t = threadIdx.x;
    const float* di_img = req + (size_t)(b * 8) * PPX;
    const __half* cimg  = confb + (size_t)bl * PPX;
    const int p0 = blockIdx.x * 1024 + t * 4;

    const int ab = (b * 64 + l) * 6;
    const float a00 = uload(naff + ab + 0), a01 = uload(naff + ab + 1);
    const float a02 = uload(naff + ab + 2), a10 = uload(naff + ab + 3);
    const float a11 = uload(naff + ab + 4), a12 = uload(naff + ab + 5);

    float4 di4 = *(const float4*)(di_img + p0);

    const float step  = 2.0f / (float)(HWDIM - 1);
    const float half_ = 0.5f * (float)(HWDIM - 1);
    const int y = p0 / HWDIM;              // 4 px share the row (384 % 4 == 0)
    const int x = p0 - y * HWDIM;
    const float gyv = fmaf((float)y, step, -1.0f);

    float acc = 0.0f;
    float sdi = (di4.x + di4.y) + (di4.z + di4.w);

    #pragma unroll
    for (int j = 0; j < 4; ++j) {
        const float gxv = fmaf((float)(x + j), step, -1.0f);
        float sx = a00 * gxv + a01 * gyv + a02;
        float sy = a10 * gxv + a11 * gyv + a12;
        float pxf = (sx + 1.0f) * half_;
        float pyf = (sy + 1.0f) * half_;
        float x0f = floorf(pxf), y0f = floorf(pyf);
        float wx = pxf - x0f, wy = pyf - y0f;
        int x0 = (int)x0f, y0 = (int)y0f;
        float v00 = conf_sample_h(cimg, y0,     x0);
        float v01 = conf_sample_h(cimg, y0,     x0 + 1);
        float v10 = conf_sample_h(cimg, y0 + 1, x0);
        float v11 = conf_sample_h(cimg, y0 + 1, x0 + 1);
        float top = v00 + wx * (v01 - v00);
        float bot = v10 + wx * (v11 - v10);
        acc = fmaf((&di4.x)[j], top + wy * (bot - top), acc);
    }

    for (int o = 32; o > 0; o >>= 1) acc += __shfl_down(acc, o);
    for (int o = 32; o > 0; o >>= 1) sdi += __shfl_down(sdi, o);

    if ((t & 63) == 0) {
        const int pi = blockIdx.x * 4 + (t >> 6);
        ws[PART_O_OFF + bl * NPART + pi] = acc;
        if (l == 0) ws[PART_D_OFF + b * NPART + pi] = sdi;
    }
}

// ---- Fallback single-pass (ws too small for conf cache), atomic-free -------
__device__ __forceinline__ float conf_sample(const float* __restrict__ img0,
                                             int yi, int xi) {
    bool valid = ((unsigned)xi < HWDIM) && ((unsigned)yi < HWDIM);
    int yc = min(max(yi, 0), HWDIM - 1);
    int xc = min(max(xi, 0), HWDIM - 1);
    int off = yc * HWDIM + xc;
    return valid ? fast_sigmoid(fmaxf(img0[off], img0[off + PPX])) : 0.0f;
}

__global__ __launch_bounds__(256) void heavy_kernel(
    const float* __restrict__ psm, const float* __restrict__ req,
    const float* __restrict__ naff, float* __restrict__ ws)
{
    const int bl = blockIdx.y;
    const int b = bl >> 3;
    const int l = bl & 7;
    const int t = threadIdx.x;
    const float* img0   = psm + (size_t)bl * (2 * PPX);
    const float* di_img = req + (size_t)(b * 8) * PPX;
    const int ab = (b * 64 + l) * 6;
    const float a00 = uload(naff + ab + 0), a01 = uload(naff + ab + 1);
    const float a02 = uload(naff + ab + 2), a10 = uload(naff + ab + 3);
    const float a11 = uload(naff + ab + 4), a12 = uload(naff + ab + 5);

    const int p0 = blockIdx.x * 1024 + t * 4;
    const float step  = 2.0f / (float)(HWDIM - 1);
    const float half_ = 0.5f * (float)(HWDIM - 1);
    const int y = p0 / HWDIM;
    const int x = p0 - y * HWDIM;
    const float gyv = fmaf((float)y, step, -1.0f);

    float4 di4 = *(const float4*)(di_img + p0);
    float s_conf = 0.0f, s_ov = 0.0f;
    float s_di = (di4.x + di4.y) + (di4.z + di4.w);

    #pragma unroll
    for (int j = 0; j < 4; ++j) {
        const int p = p0 + j;
        s_conf += fast_sigmoid(fmaxf(img0[p], img0[p + PPX]));
        const float gxv = fmaf((float)(x + j), step, -1.0f);
        float sx = a00 * gxv + a01 * gyv + a02;
        float sy = a10 * gxv + a11 * gyv + a12;
        float pxf = (sx + 1.0f) * half_;
        float pyf = (sy + 1.0f) * half_;
        float x0f = floorf(pxf), y0f = floorf(pyf);
        float wx = pxf - x0f, wy = pyf - y0f;
        int x0 = (int)x0f, y0 = (int)y0f;
        float v00 = conf_sample(img0, y0,     x0);
        float v01 = conf_sample(img0, y0,     x0 + 1);
        float v10 = conf_sample(img0, y0 + 1, x0);
        float v11 = conf_sample(img0, y0 + 1, x0 + 1);
        float top = v00 + wx * (v01 - v00);
        float bot = v10 + wx * (v11 - v10);
        s_ov = fmaf((&di4.x)[j], top + wy * (bot - top), s_ov);
    }

    for (int o = 32; o > 0; o >>= 1) {
        s_conf += __shfl_down(s_conf, o);
        s_ov   += __shfl_down(s_ov,   o);
        s_di   += __shfl_down(s_di,   o);
    }
    if ((t & 63) == 0) {
        const int pi = blockIdx.x * 4 + (t >> 6);
        ws[PART_A_OFF + bl * NPART + pi] = s_conf;
        ws[PART_O_OFF + bl * NPART + pi] = s_ov;
        if (l == 0) ws[PART_D_OFF + b * NPART + pi] = s_di;
    }
}

// ---- Reduce partials -> sums[272]. One wave per output value. --------------
__global__ __launch_bounds__(64) void reduce_kernel(float* __restrict__ ws) {
    const int idx = blockIdx.x;                  // 0..271
    const int t = threadIdx.x;
    const float* src;
    if (idx < NBL)          src = ws + PART_A_OFF + idx * NPART;
    else if (idx < 2 * NBL) src = ws + PART_O_OFF + (idx - NBL) * NPART;
    else                    src = ws + PART_D_OFF + (idx - 2 * NBL) * NPART;
    float s = 0.0f;
    for (int k = t; k < NPART; k += 64) s += src[k];
    for (int o = 32; o > 0; o >>= 1) s += __shfl_down(s, o);
    if (t == 0) ws[SUMS_OFF + idx] = s;
}

// ---- Tiny MLP head (one wave per (b,l)) ------------------------------------
__global__ __launch_bounds__(64) void mlp_kernel(
    const float* __restrict__ sums, const float* __restrict__ naff,
    const float* __restrict__ qW1, const float* __restrict__ qb1,
    const float* __restrict__ qW2, const float* __restrict__ qb2,
    const float* __restrict__ kW1, const float* __restrict__ kb1,
    const float* __restrict__ kW2, const float* __restrict__ kb2,
    const float* __restrict__ eW1, const float* __restrict__ eb1,
    const float* __restrict__ eW2, const float* __restrict__ eb2,
    float* __restrict__ out)
{
    const int bl = blockIdx.x;
    const int b = bl >> 3;
    const int l = bl & 7;
    const int t = threadIdx.x;
    const float invP = 1.0f / (float)PPX;

    const float demand = sums[2 * NBL + b] * invP;
    const float mc0    = sums[b * 8] * invP;
    const float mc     = sums[bl] * invP;
    const float ov     = sums[NBL + bl] * invP;

    const int abase = (b * 64 + l) * 6;
    const float dx = naff[abase + 2];
    const float dy = naff[abase + 5];
    const float dist = sqrtf(dx * dx + dy * dy);

    const int dbase  = (b * 64 + 9 * l) * 6;
    const int dbase0 = (b * 64) * 6;
    const float yawl = atan2f(naff[dbase + 3],  naff[dbase + 0]);
    const float yaw0 = atan2f(naff[dbase0 + 3], naff[dbase0 + 0]);
    const float tt = yaw0 - yawl;        // cos/sin(atan2(sin t,cos t))==cos/sin(t)
    const float cosd = cosf(tt), sind = sinf(tt);

    const float ego[8] = {mc0, demand, 0.0f, 0.0f, 1.0f, 0.0f, 0.0f, demand};
    const float fj[8]  = {mc, ov, dx, dy, cosd, sind, dist, demand};

    __shared__ float sh[64];
    __shared__ float qv[64];
    __shared__ float kv[64];

    float h = qb1[t];
    for (int i = 0; i < 8; ++i) h = fmaf(ego[i], qW1[i * 64 + t], h);
    sh[t] = fmaxf(h, 0.0f);
    __syncthreads();
    float q2 = qb2[t];
    for (int i = 0; i < 64; ++i) q2 = fmaf(sh[i], qW2[i * 64 + t], q2);
    qv[t] = q2;
    __syncthreads();

    float hk = kb1[t];
    for (int i = 0; i < 8; ++i) hk = fmaf(fj[i], kW1[i * 64 + t], hk);
    sh[t] = fmaxf(hk, 0.0f);
    __syncthreads();
    float k2 = kb2[t];
    for (int i = 0; i < 64; ++i) k2 = fmaf(sh[i], kW2[i * 64 + t], k2);
    kv[t] = k2;
    __syncthreads();

    float he = eb1[t];
    for (int i = 0; i < 64; ++i) he = fmaf(qv[i], eW1[i * 64 + t], he);
    for (int i = 0; i < 64; ++i) he = fmaf(kv[i], eW1[(64 + i) * 64 + t], he);
    he = fmaxf(he, 0.0f);

    float part = he * eW2[t];
    for (int o = 32; o > 0; o >>= 1) part += __shfl_down(part, o);

    if (t == 0) {
        float r;
        if (l == 0) {
            r = 0.0f;                    // logits[:,0] = -1e9 -> sigmoid -> 0
        } else {
            float logit = part + eb2[0];
            r = 1.0f / (1.0f + expf(-logit));
            r = fminf(fmaxf(r, 0.0f), 1.0f);
        }
        out[bl] = r;
    }
}

extern "C" void kernel_launch(void* const* d_in, const int* in_sizes, int n_in,
                              void* d_out, int out_size, void* d_ws, size_t ws_size,
                              hipStream_t stream) {
    const float* psm  = (const float*)d_in[0];
    const float* req  = (const float*)d_in[1];
    const float* naff = (const float*)d_in[2];
    const float* qW1 = (const float*)d_in[4];
    const float* qb1 = (const float*)d_in[5];
    const float* qW2 = (const float*)d_in[6];
    const float* qb2 = (const float*)d_in[7];
    const float* kW1 = (const float*)d_in[8];
    const float* kb1 = (const float*)d_in[9];
    const float* kW2 = (const float*)d_in[10];
    const float* kb2 = (const float*)d_in[11];
    const float* eW1 = (const float*)d_in[12];
    const float* eb1 = (const float*)d_in[13];
    const float* eW2 = (const float*)d_in[14];
    const float* eb2 = (const float*)d_in[15];
    float* out = (float*)d_out;
    float* ws  = (float*)d_ws;

    if (ws_size >= CONF_OFF_B + CONF_BYTES) {
        __half* confb = (__half*)((char*)d_ws + CONF_OFF_B);
        hipLaunchKernelGGL(conf_kernel, dim3(144, NBL), dim3(256), 0, stream,
                           psm, confb, ws);
        hipLaunchKernelGGL(overlap_kernel, dim3(144, NBL), dim3(256), 0, stream,
                           req, naff, confb, ws);
    } else {
        hipLaunchKernelGGL(heavy_kernel, dim3(144, NBL), dim3(256), 0, stream,
                           psm, req, naff, ws);
    }

    hipLaunchKernelGGL(reduce_kernel, dim3(2 * NBL + NB), dim3(64), 0, stream, ws);
    hipLaunchKernelGGL(mlp_kernel, dim3(NBL), dim3(64), 0, stream,
                       ws + SUMS_OFF, naff,
                       qW1, qb1, qW2, qb2, kW1, kb1, kW2, kb2,
                       eW1, eb1, eW2, eb2, out);
}